// Round 7
// baseline (102.636 us; speedup 1.0000x reference)
//
#include <hip/hip_runtime.h>
#include <math.h>

// Problem constants
#define NA   12            // atoms per residue
#define NL   256           // residues
#define NN   3072          // NL*NA atoms per batch
#define NB   2             // batches
#define ED   32            // embedding dim
#define KNB  30            // neighbours
#define BIGD 1000000.0f

// Flat output offsets (all stored as float32; int outputs stored as float values)
#define OFF_COORDS 0                       // 2*3072*3   = 18432
#define OFF_MASK   18432                   // 2*3072     = 6144
#define OFF_ENC    24576                   // 2*3072*32  = 196608
#define OFF_DIST   221184                  // 2*3072*30  = 184320
#define OFF_IDX    405504                  // 2*3072*30  = 184320

// key packing: top 20 bits = float bits of SQUARED dist (positive -> uint order
// == float order; sqrt is monotone so d^2-selection == d-selection), low 12
// bits = atom index (0..3071). min(key) == lexicographic (dist, idx) min with
// smallest-index tie-break == jax top_k semantics.
#define KEYVAL 0xFFFFF000u
#define KEYIDX 0x00000FFFu
#define MASKED_D2 1e12f    // sqrt -> ~1e6 == BIGD (trunc err ~122 abs << 2e4 threshold)

static __device__ __forceinline__ unsigned umin32(unsigned a, unsigned b) {
    return a < b ? a : b;
}

#define DPP_MIN_STEP(CTRL)                                                        \
    {                                                                             \
        int t_ = __builtin_amdgcn_update_dpp(v_, v_, (CTRL), 0xf, 0xf, false);    \
        v_ = (int)umin32((unsigned)v_, (unsigned)t_);                             \
    }

#define TREE8(A0,A1,A2,A3,A4,A5,A6,A7) \
    umin32(umin32(umin32((A0),(A1)), umin32((A2),(A3))), \
           umin32(umin32((A4),(A5)), umin32((A6),(A7))))

#define REMOVE_RESCAN(G)                                                          \
    {                                                                             \
        _Pragma("unroll")                                                         \
        for (int u = 0; u < 8; ++u) {                                             \
            const int t = (G) * 8 + u;                                            \
            k[t] = (k[t] == wkey) ? 0xFFFFFFFFu : k[t];                           \
        }                                                                         \
        gm[(G)] = TREE8(k[(G)*8+0],k[(G)*8+1],k[(G)*8+2],k[(G)*8+3],              \
                        k[(G)*8+4],k[(G)*8+5],k[(G)*8+6],k[(G)*8+7]);             \
    }

// ---------------------------------------------------------------------------
// Single fused kernel. 384 blocks x 512 threads (8 waves), ALL co-resident
// (<=2 blocks/CU: 96 KB LDS, 16 waves, 128 VGPR) -> one scheduling round.
// Blocks 0..191 -> batch 0, 192..383 -> batch 1; block handles 16 rows
// (2 rows per wave, sequential).
// Phase 1: stage 3072 {x,y,z,mask} float4 into 48 KB LDS via coalesced
//          float4 loads (3 loads = 4 atoms per task).
// Phase 2: per-wave top-30 from LDS (round-5 extraction core, unchanged).
// Phase 3: prep tail; 384*512 threads == exactly the 196608 enc elements.
// ---------------------------------------------------------------------------
__global__ __launch_bounds__(512, 4) void fused_kernel(const float* __restrict__ coords,
                                                       const int* __restrict__ mask,
                                                       const float* __restrict__ emb,
                                                       const float* __restrict__ scale,
                                                       const float* __restrict__ shift,
                                                       float* __restrict__ out) {
    __shared__ float4 sc4[NN];        // 48 KB

    int tid  = threadIdx.x;
    int lane = tid & 63;
    int wave = tid >> 6;              // 0..7
    int b    = (int)(blockIdx.x) / 192;
    int rblk = (int)(blockIdx.x) - b * 192;
    const float4* cg4 = (const float4*)(coords + (size_t)b * NN * 3); // 2304 float4
    const int*    mb  = mask + b * NL;

    // ---- Phase 1: stage packed coords+mask into LDS ----
    // Task t covers atoms 4t..4t+3 (floats 12t..12t+11 = float4 3t..3t+2).
    for (int task = tid; task < NN / 4; task += 512) {
        float4 f0 = cg4[3 * task + 0];
        float4 f1 = cg4[3 * task + 1];
        float4 f2 = cg4[3 * task + 2];
        int base = 4 * task;
        float m0 = (float)mb[((base + 0) * 43691) >> 19];
        float m1 = (float)mb[((base + 1) * 43691) >> 19];
        float m2 = (float)mb[((base + 2) * 43691) >> 19];
        float m3 = (float)mb[((base + 3) * 43691) >> 19];
        sc4[base + 0] = make_float4(f0.x, f0.y, f0.z, m0);
        sc4[base + 1] = make_float4(f0.w, f1.x, f1.y, m1);
        sc4[base + 2] = make_float4(f1.z, f1.w, f2.x, m2);
        sc4[base + 3] = make_float4(f2.y, f2.z, f2.w, m3);
    }
    __syncthreads();

    // ---- Phase 2: per-wave top-30, two rows sequentially ----
#pragma unroll 1
    for (int rr = 0; rr < 2; ++rr) {
        int i   = rblk * 16 + wave + rr * 8;   // row within batch, 0..3071
        int row = b * NN + i;                  // global output row
        float4 q = sc4[i];                     // uniform address -> LDS broadcast

        if (q.w != 0.f) {
            unsigned k[48];
            unsigned gm[6];

#pragma unroll
            for (int t = 0; t < 48; ++t) {
                int j = t * 64 + lane;
                float4 v = sc4[j];
                float dx = v.x - q.x, dy = v.y - q.y, dz = v.z - q.z;
                float s = dx * dx + dy * dy + dz * dz + 1e-6f;   // squared dist
                s = (v.w != 0.f) ? s : MASKED_D2;
                k[t] = (__float_as_uint(s) & KEYVAL) | (unsigned)j;
            }
#pragma unroll
            for (int g = 0; g < 6; ++g)
                gm[g] = TREE8(k[g*8+0],k[g*8+1],k[g*8+2],k[g*8+3],
                              k[g*8+4],k[g*8+5],k[g*8+6],k[g*8+7]);

            unsigned cur = umin32(umin32(umin32(gm[0], gm[1]), umin32(gm[2], gm[3])),
                                  umin32(gm[4], gm[5]));
            unsigned rkey = 0u;

            for (int it = 0; it < KNB; ++it) {
                // 4-step DPP min ladder -> row16 minima; readlane + scalar mins.
                int v_ = (int)cur;
                DPP_MIN_STEP(0xB1)   // quad_perm [1,0,3,2]  (xor 1)
                DPP_MIN_STEP(0x4E)   // quad_perm [2,3,0,1]  (xor 2)
                DPP_MIN_STEP(0x141)  // row_half_mirror      (octet min)
                DPP_MIN_STEP(0x140)  // row_mirror           (row16 min)
                unsigned r0  = (unsigned)__builtin_amdgcn_readlane(v_, 0);
                unsigned r16 = (unsigned)__builtin_amdgcn_readlane(v_, 16);
                unsigned r32 = (unsigned)__builtin_amdgcn_readlane(v_, 32);
                unsigned r48 = (unsigned)__builtin_amdgcn_readlane(v_, 48);
                unsigned wkey = umin32(umin32(r0, r16), umin32(r32, r48)); // SGPR
                rkey = (lane == it) ? wkey : rkey;

                int wg = (int)((wkey & KEYIDX) >> 9);  // j>>6 = slot, slot>>3 = grp
                switch (wg) {                           // scalar branch
                    case 0: REMOVE_RESCAN(0); break;
                    case 1: REMOVE_RESCAN(1); break;
                    case 2: REMOVE_RESCAN(2); break;
                    case 3: REMOVE_RESCAN(3); break;
                    case 4: REMOVE_RESCAN(4); break;
                    default: REMOVE_RESCAN(5); break;
                }
                cur = umin32(umin32(umin32(gm[0], gm[1]), umin32(gm[2], gm[3])),
                             umin32(gm[4], gm[5]));
            }

            if (lane < KNB) {
                float d2 = __uint_as_float(rkey & KEYVAL);
                out[OFF_DIST + (size_t)row * KNB + lane] = sqrtf(d2);
                out[OFF_IDX  + (size_t)row * KNB + lane] = (float)(rkey & KEYIDX);
            }
        } else {
            if (lane < KNB) {
                out[OFF_DIST + (size_t)row * KNB + lane] = BIGD;
                out[OFF_IDX  + (size_t)row * KNB + lane] = 0.f;
            }
        }
    }

    // ---- Phase 3: prep tail (enc + coords reshape + mask expand) ----
    // 384*512 threads == 196608 == exactly all enc elements; block batch == b.
    int gidx = (int)blockIdx.x * 512 + tid;

    {
        // wave-level mask sum for batch b (int4: 64 lanes x 4 = 256 residues)
        const int4* m4 = (const int4*)(mask + b * NL);
        int4 mv = m4[lane];
        float S = (float)(mv.x + mv.y + mv.z + mv.w);
#pragma unroll
        for (int m = 1; m < 64; m <<= 1) S += __shfl_xor(S, m);

        int c = gidx & (ED - 1);
        float colsum = 0.f, sumsq = 0.f;
#pragma unroll
        for (int a = 0; a < NA; ++a) {
            float e = emb[a * ED + c];
            colsum += e; sumsq += e * e;
        }
        float cnt  = fmaxf(12.0f * S, 1.0f);
        float mean = S * colsum / cnt;
        // sum_a (e_a - mean)^2 = sumsq - 2*mean*colsum + 12*mean^2
        float acc  = sumsq - 2.0f * mean * colsum + 12.0f * mean * mean;
        float var  = (S * acc + ((float)NN - 12.0f * S) * mean * mean) / cnt;
        float rstd = 1.0f / sqrtf(var + 1e-5f);

        int n  = (gidx >> 5) - b * NN;             // atom index 0..3071
        int nr = (n * 43691) >> 19;                // n / 12
        float mi = sc4[n].w;                       // mask from LDS (broadcast-ish)
        float v = 0.f;
        if (mi != 0.f) {
            float en = emb[(n - nr * NA) * ED + c];
            v = (en - mean) * rstd * scale[c] + shift[c];
        }
        out[OFF_ENC + gidx] = v;
    }

    if (gidx < NB * NN * 3) {                      // 18432: pure reshape copy
        out[OFF_COORDS + gidx] = coords[gidx];
    }

    if (gidx < NB * NN) {                          // 6144: mask expand
        int bb = gidx >= NN ? 1 : 0;
        int nn = gidx - bb * NN;
        int nr = (nn * 43691) >> 19;               // nn / 12
        out[OFF_MASK + gidx] = (float)mask[bb * NL + nr];
    }
}

// ---------------------------------------------------------------------------
extern "C" void kernel_launch(void* const* d_in, const int* in_sizes, int n_in,
                              void* d_out, int out_size, void* d_ws, size_t ws_size,
                              hipStream_t stream) {
    const float* coords = (const float*)d_in[0];   // (2,256,12,3)
    const int*   mask   = (const int*)d_in[1];     // (2,256)
    const float* emb    = (const float*)d_in[2];   // (12,32)
    const float* scale  = (const float*)d_in[3];   // (32)
    const float* shift  = (const float*)d_in[4];   // (32)
    float* out = (float*)d_out;

    fused_kernel<<<NB * (NN / 16), 512, 0, stream>>>(coords, mask, emb, scale, shift, out);
}

// Round 9
// 93.838 us; speedup vs baseline: 1.0938x; 1.0938x over previous
//
#include <hip/hip_runtime.h>
#include <math.h>

// Problem constants
#define NA   12            // atoms per residue
#define NL   256           // residues
#define NN   3072          // NL*NA atoms per batch
#define NB   2             // batches
#define ED   32            // embedding dim
#define KNB  30            // neighbours
#define BIGD 1000000.0f

// Flat output offsets (all stored as float32; int outputs stored as float values)
#define OFF_COORDS 0                       // 2*3072*3   = 18432
#define OFF_MASK   18432                   // 2*3072     = 6144
#define OFF_ENC    24576                   // 2*3072*32  = 196608
#define OFF_DIST   221184                  // 2*3072*30  = 184320
#define OFF_IDX    405504                  // 2*3072*30  = 184320

// key packing: top 20 bits = float bits of SQUARED dist (positive -> uint order
// == float order; sqrt monotone => d^2-selection == d-selection), low 12 bits =
// atom index. min(key) == lexicographic (dist, idx) min, smallest-index
// tie-break == jax top_k semantics. Masked candidates: s == float(1e12)
// EXACTLY for all (ulp(1e12)=131072 > any d^2), so they tie and resolve by idx.
#define KEYVAL 0xFFFFF000u
#define KEYIDX 0x00000FFFu
#define MASKED_ADD 1e12f   // additive mask term; sqrt -> ~1e6 == BIGD
#define VALID_ADD  1e-6f   // reference adds 1e-6 before sqrt

static __device__ __forceinline__ unsigned umin32(unsigned a, unsigned b) {
    return a < b ? a : b;
}

#define DPP_MIN_STEP(CTRL)                                                        \
    {                                                                             \
        int t_ = __builtin_amdgcn_update_dpp(v_, v_, (CTRL), 0xf, 0xf, false);    \
        v_ = (int)umin32((unsigned)v_, (unsigned)t_);                             \
    }

#define TREE8(A0,A1,A2,A3,A4,A5,A6,A7) \
    umin32(umin32(umin32((A0),(A1)), umin32((A2),(A3))), \
           umin32(umin32((A4),(A5)), umin32((A6),(A7))))

#define REMOVE_RESCAN(G)                                                          \
    {                                                                             \
        _Pragma("unroll")                                                         \
        for (int u = 0; u < 8; ++u) {                                             \
            const int t = (G) * 8 + u;                                            \
            k[t] = (k[t] == wkey) ? 0xFFFFFFFFu : k[t];                           \
        }                                                                         \
        gm[(G)] = TREE8(k[(G)*8+0],k[(G)*8+1],k[(G)*8+2],k[(G)*8+3],              \
                        k[(G)*8+4],k[(G)*8+5],k[(G)*8+6],k[(G)*8+7]);             \
    }

// ---------------------------------------------------------------------------
// Single fused kernel. 768 blocks x 256 threads (4 waves).
// Blocks 0..383 -> batch 0, 384..767 -> batch 1; block handles 8 rows
// (2 per wave, sequential). 3 blocks/CU co-resident (144 KB LDS), one round.
// Phase 1: stage 3072 {x,y,z,addmask} float4 into 48 KB LDS; per-element
//          scalar loads + ds_write_b128 at 16B lane stride (conflict-free,
//          verified R6/R7: the 64B-stride variant cost 442K conflicts).
// Phase 2: per-wave top-30 from LDS (R5 extraction core: packed u32 keys,
//          DPP min ladder, scalar-branched group rescan).
// Phase 3: prep tail; 768*256 threads == exactly the 196608 enc elements.
// ---------------------------------------------------------------------------
__global__ __launch_bounds__(256, 3) void fused_kernel(const float* __restrict__ coords,
                                                       const int* __restrict__ mask,
                                                       const float* __restrict__ emb,
                                                       const float* __restrict__ scale,
                                                       const float* __restrict__ shift,
                                                       float* __restrict__ out) {
    __shared__ float4 sc4[NN];        // 48 KB

    int tid  = threadIdx.x;
    int lane = tid & 63;
    int wave = tid >> 6;              // 0..3
    int b    = (int)(blockIdx.x) / 384;
    int rblk = (int)(blockIdx.x) - b * 384;
    const float* cb = coords + (size_t)b * NN * 3;
    const int*   mb = mask + b * NL;

    // ---- Phase 1: stage coords + additive mask term into LDS ----
#pragma unroll
    for (int s = 0; s < 12; ++s) {
        int e = tid + s * 256;
        int r = (e * 43691) >> 19;    // e / 12 (magic, exact for e < 4096)
        float aw = mb[r] ? VALID_ADD : MASKED_ADD;
        sc4[e] = make_float4(cb[3 * e + 0], cb[3 * e + 1], cb[3 * e + 2], aw);
    }
    __syncthreads();

    // ---- Phase 2: per-wave top-30, two rows sequentially ----
#pragma unroll 1
    for (int rr = 0; rr < 2; ++rr) {
        int i   = rblk * 8 + wave * 2 + rr;    // row within batch, 0..3071
        int row = b * NN + i;                  // global output row
        float4 q = sc4[i];                     // uniform address -> broadcast

        if (q.w < 1.0f) {                      // valid row (aw == 1e-6)
            unsigned k[48];
            unsigned gm[6];

#pragma unroll
            for (int t = 0; t < 48; ++t) {
                int j = t * 64 + lane;
                float4 v = sc4[j];
                float dx = v.x - q.x, dy = v.y - q.y, dz = v.z - q.z;
                // s = d^2 + (1e-6 | 1e12); masked collapses to exactly 1e12
                float s = fmaf(dx, dx, fmaf(dy, dy, fmaf(dz, dz, v.w)));
                k[t] = (__float_as_uint(s) & KEYVAL) | (unsigned)j;
            }
#pragma unroll
            for (int g = 0; g < 6; ++g)
                gm[g] = TREE8(k[g*8+0],k[g*8+1],k[g*8+2],k[g*8+3],
                              k[g*8+4],k[g*8+5],k[g*8+6],k[g*8+7]);

            unsigned cur = umin32(umin32(umin32(gm[0], gm[1]), umin32(gm[2], gm[3])),
                                  umin32(gm[4], gm[5]));
            unsigned rkey = 0u;

            for (int it = 0; it < KNB; ++it) {
                // 4-step DPP min ladder -> row16 minima; readlane + scalar mins.
                int v_ = (int)cur;
                DPP_MIN_STEP(0xB1)   // quad_perm [1,0,3,2]  (xor 1)
                DPP_MIN_STEP(0x4E)   // quad_perm [2,3,0,1]  (xor 2)
                DPP_MIN_STEP(0x141)  // row_half_mirror      (octet min)
                DPP_MIN_STEP(0x140)  // row_mirror           (row16 min)
                unsigned r0  = (unsigned)__builtin_amdgcn_readlane(v_, 0);
                unsigned r16 = (unsigned)__builtin_amdgcn_readlane(v_, 16);
                unsigned r32 = (unsigned)__builtin_amdgcn_readlane(v_, 32);
                unsigned r48 = (unsigned)__builtin_amdgcn_readlane(v_, 48);
                unsigned wkey = umin32(umin32(r0, r16), umin32(r32, r48)); // SGPR
                rkey = (lane == it) ? wkey : rkey;

                int wg = (int)((wkey & KEYIDX) >> 9);  // j>>6 = slot, slot>>3 = grp
                switch (wg) {                           // scalar branch
                    case 0: REMOVE_RESCAN(0); break;
                    case 1: REMOVE_RESCAN(1); break;
                    case 2: REMOVE_RESCAN(2); break;
                    case 3: REMOVE_RESCAN(3); break;
                    case 4: REMOVE_RESCAN(4); break;
                    default: REMOVE_RESCAN(5); break;
                }
                cur = umin32(umin32(umin32(gm[0], gm[1]), umin32(gm[2], gm[3])),
                             umin32(gm[4], gm[5]));
            }

            if (lane < KNB) {
                float d2 = __uint_as_float(rkey & KEYVAL);
                out[OFF_DIST + (size_t)row * KNB + lane] = sqrtf(d2);
                out[OFF_IDX  + (size_t)row * KNB + lane] = (float)(rkey & KEYIDX);
            }
        } else {
            if (lane < KNB) {
                out[OFF_DIST + (size_t)row * KNB + lane] = BIGD;
                out[OFF_IDX  + (size_t)row * KNB + lane] = 0.f;
            }
        }
    }

    // ---- Phase 3: prep tail (enc + coords reshape + mask expand) ----
    // 768*256 threads == 196608 == exactly all enc elements; block batch == b.
    int gidx = (int)blockIdx.x * 256 + tid;

    {
        // wave-level mask sum for batch b (int4: 64 lanes x 4 = 256 residues)
        const int4* m4 = (const int4*)(mask + b * NL);
        int4 mv = m4[lane];
        float S = (float)(mv.x + mv.y + mv.z + mv.w);
#pragma unroll
        for (int m = 1; m < 64; m <<= 1) S += __shfl_xor(S, m);

        int c = gidx & (ED - 1);
        float colsum = 0.f, sumsq = 0.f;
#pragma unroll
        for (int a = 0; a < NA; ++a) {
            float e = emb[a * ED + c];
            colsum += e; sumsq += e * e;
        }
        float cnt  = fmaxf(12.0f * S, 1.0f);
        float mean = S * colsum / cnt;
        // sum_a (e_a - mean)^2 = sumsq - 2*mean*colsum + 12*mean^2
        float acc  = sumsq - 2.0f * mean * colsum + 12.0f * mean * mean;
        float var  = (S * acc + ((float)NN - 12.0f * S) * mean * mean) / cnt;
        float rstd = 1.0f / sqrtf(var + 1e-5f);

        int n  = (gidx >> 5) - b * NN;             // atom index 0..3071
        int nr = (n * 43691) >> 19;                // n / 12
        float v = 0.f;
        if (sc4[n].w < 1.0f) {                     // valid atom (aw == 1e-6)
            float en = emb[(n - nr * NA) * ED + c];
            v = (en - mean) * rstd * scale[c] + shift[c];
        }
        out[OFF_ENC + gidx] = v;
    }

    if (gidx < NB * NN * 3) {                      // 18432: pure reshape copy
        out[OFF_COORDS + gidx] = coords[gidx];
    }

    if (gidx < NB * NN) {                          // 6144: mask expand
        int bb = gidx >= NN ? 1 : 0;
        int nn = gidx - bb * NN;
        int nr = (nn * 43691) >> 19;               // nn / 12
        out[OFF_MASK + gidx] = (float)mask[bb * NL + nr];
    }
}

// ---------------------------------------------------------------------------
extern "C" void kernel_launch(void* const* d_in, const int* in_sizes, int n_in,
                              void* d_out, int out_size, void* d_ws, size_t ws_size,
                              hipStream_t stream) {
    const float* coords = (const float*)d_in[0];   // (2,256,12,3)
    const int*   mask   = (const int*)d_in[1];     // (2,256)
    const float* emb    = (const float*)d_in[2];   // (12,32)
    const float* scale  = (const float*)d_in[3];   // (32)
    const float* shift  = (const float*)d_in[4];   // (32)
    float* out = (float*)d_out;

    fused_kernel<<<NB * (NN / 8), 256, 0, stream>>>(coords, mask, emb, scale, shift, out);
}

// Round 10
// 86.796 us; speedup vs baseline: 1.1825x; 1.0811x over previous
//
#include <hip/hip_runtime.h>
#include <math.h>

// Problem constants
#define NA   12            // atoms per residue
#define NL   256           // residues
#define NN   3072          // NL*NA atoms per batch
#define NB   2             // batches
#define ED   32            // embedding dim
#define KNB  30            // neighbours
#define BIGD 1000000.0f

// Flat output offsets (all stored as float32; int outputs stored as float values)
#define OFF_COORDS 0                       // 2*3072*3   = 18432
#define OFF_MASK   18432                   // 2*3072     = 6144
#define OFF_ENC    24576                   // 2*3072*32  = 196608
#define OFF_DIST   221184                  // 2*3072*30  = 184320
#define OFF_IDX    405504                  // 2*3072*30  = 184320

// ws layout: byte 512+: packed float4 coords {x,y,z,addterm}
#define WS_C4_BYTE_OFF 512
#define WS_NEEDED (WS_C4_BYTE_OFF + (size_t)NB * NN * 16)

// key packing: top 20 bits = float bits of SQUARED dist (positive -> uint order
// == float order; sqrt monotone => d^2-selection == d-selection), low 12 bits =
// atom index. min(key) == lexicographic (dist, idx) min, smallest-index
// tie-break == jax top_k semantics. Masked candidates: s == float(1e12)
// EXACTLY (ulp(1e12)=131072 > 2*max d^2), so they tie and resolve by idx.
#define KEYVAL 0xFFFFF000u
#define KEYIDX 0x00000FFFu
#define MASKED_ADD 1e12f   // additive mask term; sqrt -> ~1e6 == BIGD
#define VALID_ADD  1e-6f   // reference adds 1e-6 before sqrt

static __device__ __forceinline__ unsigned umin32(unsigned a, unsigned b) {
    return a < b ? a : b;
}

#define DPP_MIN_STEP(CTRL)                                                        \
    {                                                                             \
        int t_ = __builtin_amdgcn_update_dpp(v_, v_, (CTRL), 0xf, 0xf, false);    \
        v_ = (int)umin32((unsigned)v_, (unsigned)t_);                             \
    }

#define TREE8(A0,A1,A2,A3,A4,A5,A6,A7) \
    umin32(umin32(umin32((A0),(A1)), umin32((A2),(A3))), \
           umin32(umin32((A4),(A5)), umin32((A6),(A7))))

#define REMOVE_RESCAN(G)                                                          \
    {                                                                             \
        _Pragma("unroll")                                                         \
        for (int u = 0; u < 8; ++u) {                                             \
            const int t = (G) * 8 + u;                                            \
            k[t] = (k[t] == wkey) ? 0xFFFFFFFFu : k[t];                           \
        }                                                                         \
        gm[(G)] = TREE8(k[(G)*8+0],k[(G)*8+1],k[(G)*8+2],k[(G)*8+3],              \
                        k[(G)*8+4],k[(G)*8+5],k[(G)*8+6],k[(G)*8+7]);             \
    }

// ---------------------------------------------------------------------------
// Kernel 1: fused stats + encode + atom_coords copy + atom_mask expand +
//           packed float4 {x,y,z,addterm} for topk.
// ---------------------------------------------------------------------------
__global__ __launch_bounds__(256) void prep_kernel(const float* __restrict__ coords,
                                                   const int* __restrict__ mask,
                                                   const float* __restrict__ emb,
                                                   const float* __restrict__ scale,
                                                   const float* __restrict__ shift,
                                                   float* __restrict__ out,
                                                   float4* __restrict__ c4pack) {
    int idx  = blockIdx.x * 256 + threadIdx.x;     // 0..196607, enc element
    int lane = threadIdx.x & 63;
    int b = idx / (NN * ED);                       // batch (block-uniform)

    // wave-level mask sum for batch b (int4 load: 64 lanes x 4 = 256 residues)
    const int4* m4 = (const int4*)(mask + b * NL);
    int4 mv = m4[lane];
    float S = (float)(mv.x + mv.y + mv.z + mv.w);
#pragma unroll
    for (int m = 1; m < 64; m <<= 1) S += __shfl_xor(S, m);

    // per-channel analytic graph-norm stats
    int c = idx & (ED - 1);
    float colsum = 0.f, sumsq = 0.f;
#pragma unroll
    for (int a = 0; a < NA; ++a) {
        float e = emb[a * ED + c];
        colsum += e; sumsq += e * e;
    }
    float cnt  = fmaxf(12.0f * S, 1.0f);
    float mean = S * colsum / cnt;
    // sum_a (e_a - mean)^2 = sumsq - 2*mean*colsum + 12*mean^2
    float acc  = sumsq - 2.0f * mean * colsum + 12.0f * mean * mean;
    float var  = (S * acc + ((float)NN - 12.0f * S) * mean * mean) / cnt;
    float rstd = 1.0f / sqrtf(var + 1e-5f);

    // encode output
    int n  = (idx >> 5) % NN;
    int nr = (n * 43691) >> 19;                    // n / 12 (magic)
    int mi = mask[b * NL + nr];
    float v = 0.f;
    if (mi) {
        float en = emb[(n - nr * NA) * ED + c];
        v = (en - mean) * rstd * scale[c] + shift[c];
    }
    out[OFF_ENC + idx] = v;

    if (idx < NB * NN * 3) {
        out[OFF_COORDS + idx] = coords[idx];       // pure reshape
    }
    if (idx < NB * NN) {
        int bb = idx >= NN ? 1 : 0;
        int nn = idx - bb * NN;
        int rr = (nn * 43691) >> 19;               // nn / 12
        int m  = mask[bb * NL + rr];
        out[OFF_MASK + idx] = (float)m;
        if (c4pack) {
            float4 p;
            p.x = coords[idx * 3 + 0];
            p.y = coords[idx * 3 + 1];
            p.z = coords[idx * 3 + 2];
            p.w = m ? VALID_ADD : MASKED_ADD;
            c4pack[idx] = p;
        }
    }
}

// ---------------------------------------------------------------------------
// Kernel 2: per-row top-30. One wave per row (4 rows per 256-thread block).
// No LDS, no barriers: c4 reads stay L2-resident (48 KB/batch), max TLP.
// 48 packed d^2-keys per lane in VGPRs; 6 cached group-min keys; all compares
// v_min_u32; scalar-branched 8-element removal+rescan per extraction;
// 4-step DPP min ladder + readlane/s_min (SALU offload).
// __launch_bounds__(256,2): the R5-measured-good config (no AGPR split).
// ---------------------------------------------------------------------------
template <bool PACKED>
__global__ __launch_bounds__(256, 2) void topk_kernel(const float4* __restrict__ c4,
                                                      const float* __restrict__ coords,
                                                      const int* __restrict__ mask,
                                                      float* __restrict__ out) {
    int lane = threadIdx.x & 63;
    int row  = blockIdx.x * 4 + (threadIdx.x >> 6);   // 0..6143, one wave per row
    int b = (row >= NN) ? 1 : 0;
    int i = row - b * NN;

    // own row validity + query coords
    float qx, qy, qz, qw;
    if (PACKED) {
        float4 q4 = c4[b * NN + i];
        qx = q4.x; qy = q4.y; qz = q4.z; qw = q4.w;
    } else {
        const float* cb = coords + (size_t)b * NN * 3;
        qx = cb[i * 3 + 0]; qy = cb[i * 3 + 1]; qz = cb[i * 3 + 2];
        qw = mask[b * NL + ((i * 43691) >> 19)] ? VALID_ADD : MASKED_ADD;
    }
    if (qw >= 1.0f) {                // padded row: dist=BIG, idx=0
        if (lane < KNB) {
            out[OFF_DIST + (size_t)row * KNB + lane] = BIGD;
            out[OFF_IDX  + (size_t)row * KNB + lane] = 0.f;
        }
        return;
    }

    unsigned k[48];
    unsigned gm[6];

#pragma unroll
    for (int t = 0; t < 48; ++t) {
        int j = t * 64 + lane;
        float x, y, z, w;
        if (PACKED) {
            float4 v = c4[b * NN + j];
            x = v.x; y = v.y; z = v.z; w = v.w;
        } else {
            const float* cb = coords + (size_t)b * NN * 3;
            int r = (j * 43691) >> 19;          // j / 12 (magic)
            w = mask[b * NL + r] ? VALID_ADD : MASKED_ADD;
            x = cb[j * 3 + 0]; y = cb[j * 3 + 1]; z = cb[j * 3 + 2];
        }
        float dx = x - qx, dy = y - qy, dz = z - qz;
        // s = d^2 + (1e-6 | 1e12); masked collapses to exactly 1e12
        float s = fmaf(dx, dx, fmaf(dy, dy, fmaf(dz, dz, w)));
        k[t] = (__float_as_uint(s) & KEYVAL) | (unsigned)j;
    }
#pragma unroll
    for (int g = 0; g < 6; ++g)
        gm[g] = TREE8(k[g*8+0],k[g*8+1],k[g*8+2],k[g*8+3],
                      k[g*8+4],k[g*8+5],k[g*8+6],k[g*8+7]);

    unsigned cur = umin32(umin32(umin32(gm[0], gm[1]), umin32(gm[2], gm[3])),
                          umin32(gm[4], gm[5]));
    unsigned rkey = 0u;

    for (int it = 0; it < KNB; ++it) {
        // 4-step DPP min ladder -> row16 minima; readlane + scalar mins.
        int v_ = (int)cur;
        DPP_MIN_STEP(0xB1)   // quad_perm [1,0,3,2]  (xor 1)
        DPP_MIN_STEP(0x4E)   // quad_perm [2,3,0,1]  (xor 2)
        DPP_MIN_STEP(0x141)  // row_half_mirror      (octet min)
        DPP_MIN_STEP(0x140)  // row_mirror           (row16 min)
        unsigned r0  = (unsigned)__builtin_amdgcn_readlane(v_, 0);
        unsigned r16 = (unsigned)__builtin_amdgcn_readlane(v_, 16);
        unsigned r32 = (unsigned)__builtin_amdgcn_readlane(v_, 32);
        unsigned r48 = (unsigned)__builtin_amdgcn_readlane(v_, 48);
        unsigned wkey = umin32(umin32(r0, r16), umin32(r32, r48));   // SGPR
        rkey = (lane == it) ? wkey : rkey;

        int wg = (int)((wkey & KEYIDX) >> 9);      // j>>6 = slot, slot>>3 = group
        switch (wg) {                               // scalar branch
            case 0: REMOVE_RESCAN(0); break;
            case 1: REMOVE_RESCAN(1); break;
            case 2: REMOVE_RESCAN(2); break;
            case 3: REMOVE_RESCAN(3); break;
            case 4: REMOVE_RESCAN(4); break;
            default: REMOVE_RESCAN(5); break;
        }
        cur = umin32(umin32(umin32(gm[0], gm[1]), umin32(gm[2], gm[3])),
                     umin32(gm[4], gm[5]));
    }

    if (lane < KNB) {
        float d2 = __uint_as_float(rkey & KEYVAL);
        out[OFF_DIST + (size_t)row * KNB + lane] = sqrtf(d2);
        out[OFF_IDX  + (size_t)row * KNB + lane] = (float)(rkey & KEYIDX);
    }
}

// ---------------------------------------------------------------------------
extern "C" void kernel_launch(void* const* d_in, const int* in_sizes, int n_in,
                              void* d_out, int out_size, void* d_ws, size_t ws_size,
                              hipStream_t stream) {
    const float* coords = (const float*)d_in[0];   // (2,256,12,3)
    const int*   mask   = (const int*)d_in[1];     // (2,256)
    const float* emb    = (const float*)d_in[2];   // (12,32)
    const float* scale  = (const float*)d_in[3];   // (32)
    const float* shift  = (const float*)d_in[4];   // (32)
    float* out = (float*)d_out;

    bool packed = (ws_size >= WS_NEEDED);
    float4* c4 = packed ? (float4*)((char*)d_ws + WS_C4_BYTE_OFF) : nullptr;

    prep_kernel<<<(NB * NN * ED) / 256, 256, 0, stream>>>(
        coords, mask, emb, scale, shift, out, c4);
    if (packed) {
        topk_kernel<true><<<(NB * NN) / 4, 256, 0, stream>>>(c4, coords, mask, out);
    } else {
        topk_kernel<false><<<(NB * NN) / 4, 256, 0, stream>>>(nullptr, coords, mask, out);
    }
}

// Round 11
// 86.517 us; speedup vs baseline: 1.1863x; 1.0032x over previous
//
#include <hip/hip_runtime.h>
#include <math.h>

// Problem constants
#define NA   12            // atoms per residue
#define NL   256           // residues
#define NN   3072          // NL*NA atoms per batch
#define NB   2             // batches
#define ED   32            // embedding dim
#define KNB  30            // neighbours
#define BIGD 1000000.0f

// Flat output offsets (all stored as float32; int outputs stored as float values)
#define OFF_COORDS 0                       // 2*3072*3   = 18432
#define OFF_MASK   18432                   // 2*3072     = 6144
#define OFF_ENC    24576                   // 2*3072*32  = 196608
#define OFF_DIST   221184                  // 2*3072*30  = 184320
#define OFF_IDX    405504                  // 2*3072*30  = 184320

// key packing: top 20 bits = float bits of SQUARED dist (positive -> uint order
// == float order; sqrt monotone => d^2-selection == d-selection), low 12 bits =
// atom index. min(key) == lexicographic (dist, idx) min, smallest-index
// tie-break == jax top_k semantics. Masked candidates: s == float(1e12)
// EXACTLY (ulp(1e12)=131072 > 2*max d^2), so they tie and resolve by idx.
#define KEYVAL 0xFFFFF000u
#define KEYIDX 0x00000FFFu
#define MASKED_ADD 1e12f   // additive mask term; sqrt -> ~1e6 == BIGD
#define VALID_ADD  1e-6f   // reference adds 1e-6 before sqrt

#define NTOPK_BLK 1536     // topk blocks (4 rows each)
#define NPREP_BLK 768      // prep blocks

static __device__ __forceinline__ unsigned umin32(unsigned a, unsigned b) {
    return a < b ? a : b;
}

#define DPP_MIN_STEP(CTRL)                                                        \
    {                                                                             \
        int t_ = __builtin_amdgcn_update_dpp(v_, v_, (CTRL), 0xf, 0xf, false);    \
        v_ = (int)umin32((unsigned)v_, (unsigned)t_);                             \
    }

#define TREE8(A0,A1,A2,A3,A4,A5,A6,A7) \
    umin32(umin32(umin32((A0),(A1)), umin32((A2),(A3))), \
           umin32(umin32((A4),(A5)), umin32((A6),(A7))))

#define REMOVE_RESCAN(G)                                                          \
    {                                                                             \
        _Pragma("unroll")                                                         \
        for (int u = 0; u < 8; ++u) {                                             \
            const int t = (G) * 8 + u;                                            \
            k[t] = (k[t] == wkey) ? 0xFFFFFFFFu : k[t];                           \
        }                                                                         \
        gm[(G)] = TREE8(k[(G)*8+0],k[(G)*8+1],k[(G)*8+2],k[(G)*8+3],              \
                        k[(G)*8+4],k[(G)*8+5],k[(G)*8+6],k[(G)*8+7]);             \
    }

// ---------------------------------------------------------------------------
// ONE fat kernel, 2304 blocks x 256 threads.
//  blocks 0..1535   : per-row top-30 (4 rows/block, one wave per row), reading
//                     coords+mask DIRECTLY (no prep dependency; coalesced 12B
//                     stride loads, all L1/L2-resident).
//  blocks 1536..2303: prep tail (graph-norm encode, coords reshape, mask
//                     expand) -- fully independent work that fills SIMD slots
//                     beside the latency-bound topk waves.
// Extraction core bit-identical to the R5/R10 validated version (absmax 2921).
// ---------------------------------------------------------------------------
__global__ __launch_bounds__(256, 2) void fat_kernel(const float* __restrict__ coords,
                                                     const int* __restrict__ mask,
                                                     const float* __restrict__ emb,
                                                     const float* __restrict__ scale,
                                                     const float* __restrict__ shift,
                                                     float* __restrict__ out) {
    int tid = threadIdx.x;
    int bid = (int)blockIdx.x;

    if (bid < NTOPK_BLK) {
        // ================= top-k path =================
        int lane = tid & 63;
        int row  = bid * 4 + (tid >> 6);          // 0..6143, one wave per row
        int b = (row >= NN) ? 1 : 0;
        int i = row - b * NN;
        const float* cb = coords + (size_t)b * NN * 3;
        const int*   mb = mask + b * NL;

        // own row validity + query coords (wave-uniform row)
        int qvalid = mb[(i * 43691) >> 19];       // i/12 magic
        if (!qvalid) {                            // padded row: dist=BIG, idx=0
            if (lane < KNB) {
                out[OFF_DIST + (size_t)row * KNB + lane] = BIGD;
                out[OFF_IDX  + (size_t)row * KNB + lane] = 0.f;
            }
            return;
        }
        float qx = cb[i * 3 + 0], qy = cb[i * 3 + 1], qz = cb[i * 3 + 2];

        unsigned k[48];
        unsigned gm[6];

#pragma unroll
        for (int t = 0; t < 48; ++t) {
            int j = t * 64 + lane;
            int r = (j * 43691) >> 19;            // j / 12 (magic, exact <4096)
            float w = mb[r] ? VALID_ADD : MASKED_ADD;
            float x = cb[j * 3 + 0], y = cb[j * 3 + 1], z = cb[j * 3 + 2];
            float dx = x - qx, dy = y - qy, dz = z - qz;
            // s = d^2 + (1e-6 | 1e12); masked collapses to exactly 1e12
            float s = fmaf(dx, dx, fmaf(dy, dy, fmaf(dz, dz, w)));
            k[t] = (__float_as_uint(s) & KEYVAL) | (unsigned)j;
        }
#pragma unroll
        for (int g = 0; g < 6; ++g)
            gm[g] = TREE8(k[g*8+0],k[g*8+1],k[g*8+2],k[g*8+3],
                          k[g*8+4],k[g*8+5],k[g*8+6],k[g*8+7]);

        unsigned cur = umin32(umin32(umin32(gm[0], gm[1]), gm[2]),
                              umin32(umin32(gm[3], gm[4]), gm[5]));
        unsigned rkey = 0u;

        for (int it = 0; it < KNB; ++it) {
            // 4-step DPP min ladder -> row16 minima; readlane + scalar mins.
            int v_ = (int)cur;
            DPP_MIN_STEP(0xB1)   // quad_perm [1,0,3,2]  (xor 1)
            DPP_MIN_STEP(0x4E)   // quad_perm [2,3,0,1]  (xor 2)
            DPP_MIN_STEP(0x141)  // row_half_mirror      (octet min)
            DPP_MIN_STEP(0x140)  // row_mirror           (row16 min)
            unsigned r0  = (unsigned)__builtin_amdgcn_readlane(v_, 0);
            unsigned r16 = (unsigned)__builtin_amdgcn_readlane(v_, 16);
            unsigned r32 = (unsigned)__builtin_amdgcn_readlane(v_, 32);
            unsigned r48 = (unsigned)__builtin_amdgcn_readlane(v_, 48);
            unsigned wkey = umin32(umin32(r0, r16), umin32(r32, r48));  // SGPR
            rkey = (lane == it) ? wkey : rkey;

            int wg = (int)((wkey & KEYIDX) >> 9); // j>>6 = slot, slot>>3 = group
            switch (wg) {                          // scalar branch
                case 0: REMOVE_RESCAN(0); break;
                case 1: REMOVE_RESCAN(1); break;
                case 2: REMOVE_RESCAN(2); break;
                case 3: REMOVE_RESCAN(3); break;
                case 4: REMOVE_RESCAN(4); break;
                default: REMOVE_RESCAN(5); break;
            }
            cur = umin32(umin32(umin32(gm[0], gm[1]), gm[2]),
                         umin32(umin32(gm[3], gm[4]), gm[5]));
        }

        if (lane < KNB) {
            float d2 = __uint_as_float(rkey & KEYVAL);
            out[OFF_DIST + (size_t)row * KNB + lane] = sqrtf(d2);
            out[OFF_IDX  + (size_t)row * KNB + lane] = (float)(rkey & KEYIDX);
        }
    } else {
        // ================= prep path =================
        int gidx = (bid - NTOPK_BLK) * 256 + tid;  // 0..196607, enc element
        int lane = tid & 63;
        int b = gidx / (NN * ED);                  // batch (block-uniform)

        // wave-level mask sum for batch b (int4: 64 lanes x 4 = 256 residues)
        const int4* m4 = (const int4*)(mask + b * NL);
        int4 mv = m4[lane];
        float S = (float)(mv.x + mv.y + mv.z + mv.w);
#pragma unroll
        for (int m = 1; m < 64; m <<= 1) S += __shfl_xor(S, m);

        // per-channel analytic graph-norm stats
        int c = gidx & (ED - 1);
        float colsum = 0.f, sumsq = 0.f;
#pragma unroll
        for (int a = 0; a < NA; ++a) {
            float e = emb[a * ED + c];
            colsum += e; sumsq += e * e;
        }
        float cnt  = fmaxf(12.0f * S, 1.0f);
        float mean = S * colsum / cnt;
        // sum_a (e_a - mean)^2 = sumsq - 2*mean*colsum + 12*mean^2
        float acc  = sumsq - 2.0f * mean * colsum + 12.0f * mean * mean;
        float var  = (S * acc + ((float)NN - 12.0f * S) * mean * mean) / cnt;
        float rstd = 1.0f / sqrtf(var + 1e-5f);

        int n  = (gidx >> 5) % NN;
        int nr = (n * 43691) >> 19;                // n / 12 (magic)
        int mi = mask[b * NL + nr];
        float v = 0.f;
        if (mi) {
            float en = emb[(n - nr * NA) * ED + c];
            v = (en - mean) * rstd * scale[c] + shift[c];
        }
        out[OFF_ENC + gidx] = v;

        if (gidx < NB * NN * 3) {                  // 18432: pure reshape copy
            out[OFF_COORDS + gidx] = coords[gidx];
        }
        if (gidx < NB * NN) {                      // 6144: mask expand
            int bb = gidx >= NN ? 1 : 0;
            int nn = gidx - bb * NN;
            int rr = (nn * 43691) >> 19;           // nn / 12
            out[OFF_MASK + gidx] = (float)mask[bb * NL + rr];
        }
    }
}

// ---------------------------------------------------------------------------
extern "C" void kernel_launch(void* const* d_in, const int* in_sizes, int n_in,
                              void* d_out, int out_size, void* d_ws, size_t ws_size,
                              hipStream_t stream) {
    const float* coords = (const float*)d_in[0];   // (2,256,12,3)
    const int*   mask   = (const int*)d_in[1];     // (2,256)
    const float* emb    = (const float*)d_in[2];   // (12,32)
    const float* scale  = (const float*)d_in[3];   // (32)
    const float* shift  = (const float*)d_in[4];   // (32)
    float* out = (float*)d_out;

    fat_kernel<<<NTOPK_BLK + NPREP_BLK, 256, 0, stream>>>(
        coords, mask, emb, scale, shift, out);
}